// Round 2
// baseline (998.768 us; speedup 1.0000x reference)
//
#include <hip/hip_runtime.h>

// FactorizedQuantizedDistribution:
//   params [B, 255, H, W] f32 tree-node logits, sample [B, H, W] f32 in [0,1)
//   out[b] = sum_{h,w} sum_{x=0..7} v*logit - softplus(logit) along the tree path.
//
// R3: FILL-SHAPED STREAM. R2 (column-through-rows, 4KB chunks at 256KB stride per
// block) ran at ~0.8-1.6 TB/s; the harness's own fill kernel proves 6.4 TB/s for a
// plain linear march. So: one block = one whole node row (256 KB contiguous),
// grid (255 nodes, 8 batches) = 2040 blocks ~= 8/CU, nontemporal dwordx4 loads.
// Per-pixel path info comes from a 512-KB uint8 bucket table (prep kernel, d_ws,
// L2-resident; 'nt' on params keeps it from being evicted). Node level x and
// index j are block-uniform scalars; per element:
//   on  = (sv >> (8-x)) == j          (is this node on the pixel's path?)
//   bit = (sv >> (7-x)) & 1
//   contrib = (bit ? min(l,0) : -max(l,0)) - log1p(exp(-|l|))   [iff on]
// The divergent if(on) lets s_cbranch_execz skip softplus for all-off wave slices
// (~60% of slices at level 7). Same per-element formula as R2 (which passed
// absmax=0).

#define THREADS 256

typedef float v4f __attribute__((ext_vector_type(4)));

// --- Kernel A: quantize sample -> uint8 bucket table in workspace ---
__global__ __launch_bounds__(THREADS) void fqd_prep(
    const float* __restrict__ sample, unsigned* __restrict__ sv4, int total4)
{
    int gid = blockIdx.x * blockDim.x + threadIdx.x;
    if (gid >= total4) return;
    const v4f s4 = reinterpret_cast<const v4f*>(sample)[gid];
    unsigned u0 = (unsigned)(s4[0] * 256.0f) & 255u;
    unsigned u1 = (unsigned)(s4[1] * 256.0f) & 255u;
    unsigned u2 = (unsigned)(s4[2] * 256.0f) & 255u;
    unsigned u3 = (unsigned)(s4[3] * 256.0f) & 255u;
    sv4[gid] = u0 | (u1 << 8) | (u2 << 16) | (u3 << 24);
}

// --- Kernel B: one block per (node row, batch); linear 256-KB stream ---
template <bool USE_SV>
__global__ __launch_bounds__(THREADS, 4) void fqd_rows(
    const float* __restrict__ params,
    const unsigned* __restrict__ svtab,   // [B*P/4] packed bucket ids (USE_SV)
    const float* __restrict__ sample,     // fallback path (!USE_SV)
    float* __restrict__ out, int P)
{
    const int n = blockIdx.x;            // node 0..254
    const int b = blockIdx.y;
    const int nn = n + 1;
    const int x  = 31 - __clz(nn);       // tree level 0..7 (block-uniform)
    const int j  = nn - (1 << x);        // index within level
    const int s1 = 8 - x;
    const int s2 = 7 - x;

    const v4f* __restrict__ rowp =
        reinterpret_cast<const v4f*>(params + ((size_t)b * 255 + n) * (size_t)P);
    const unsigned* __restrict__ svp = svtab + (size_t)b * (P >> 2);
    const v4f* __restrict__ smp =
        reinterpret_cast<const v4f*>(sample + (size_t)b * P);

    float sum = 0.0f;
    const int iters = P / (THREADS * 4);   // 64
#pragma unroll 4
    for (int i = 0; i < iters; ++i) {
        const int q = i * THREADS + threadIdx.x;          // float4 index in row
        const v4f l4 = __builtin_nontemporal_load(rowp + q);

        unsigned w;
        if (USE_SV) {
            w = svp[q];                                    // 4 bucket ids (cached)
        } else {
            const v4f s4 = smp[q];
            w  = ((unsigned)(s4[0] * 256.0f) & 255u);
            w |= ((unsigned)(s4[1] * 256.0f) & 255u) << 8;
            w |= ((unsigned)(s4[2] * 256.0f) & 255u) << 16;
            w |= ((unsigned)(s4[3] * 256.0f) & 255u) << 24;
        }

#pragma unroll
        for (int k = 0; k < 4; ++k) {
            const unsigned svk = (w >> (8 * k)) & 255u;
            const float l = l4[k];
            if ((int)(svk >> s1) == j) {                   // on-path?
                const unsigned bit = (svk >> s2) & 1u;
                const float lin = bit ? fminf(l, 0.0f) : -fmaxf(l, 0.0f);
                sum += lin - log1pf(__expf(-fabsf(l)));
            }
        }
    }

    // Wave (64-lane) shuffle reduction, LDS across 4 waves, one atomic per block.
#pragma unroll
    for (int off = 32; off > 0; off >>= 1)
        sum += __shfl_down(sum, off, 64);

    __shared__ float red[4];
    const int lane = threadIdx.x & 63;
    const int wid  = threadIdx.x >> 6;
    if (lane == 0) red[wid] = sum;
    __syncthreads();
    if (threadIdx.x == 0) {
        atomicAdd(out + b, red[0] + red[1] + red[2] + red[3]);
    }
}

extern "C" void kernel_launch(void* const* d_in, const int* in_sizes, int n_in,
                              void* d_out, int out_size, void* d_ws, size_t ws_size,
                              hipStream_t stream) {
    const float* params = (const float*)d_in[0];
    const float* sample = (const float*)d_in[1];
    float* out = (float*)d_out;

    const int B = out_size;                    // 8
    const int P = in_sizes[1] / B;             // 65536 pixels per batch

    // d_out is poisoned before every call; zero it for the atomics.
    hipMemsetAsync(d_out, 0, (size_t)out_size * sizeof(float), stream);

    dim3 grid(255, B);                         // 2040 blocks ~= 8 per CU, no tail

    if (d_ws != nullptr && ws_size >= (size_t)B * P) {
        // Prep: 512-KB uint8 bucket table (stays L2-resident under nt stream).
        const int total4 = B * P / 4;          // 131072 packed words
        fqd_prep<<<(total4 + THREADS - 1) / THREADS, THREADS, 0, stream>>>(
            sample, (unsigned*)d_ws, total4);
        fqd_rows<true><<<grid, THREADS, 0, stream>>>(
            params, (const unsigned*)d_ws, sample, out, P);
    } else {
        // Fallback: quantize inline from sample (L2/L3-cached re-reads).
        fqd_rows<false><<<grid, THREADS, 0, stream>>>(
            params, nullptr, sample, out, P);
    }
}